// Round 2
// baseline (110.043 us; speedup 1.0000x reference)
//
#include <hip/hip_runtime.h>
#include <hip/hip_bf16.h>

// LogicConv3d: B=4, C=3, H=W=D=32, K=32, S=16 leaves, tree depth 4 (31 LUT nodes).
// Out: (B, K, 30, 30, 30) = 3,456,000 fp32 elements. ALL float tensors are fp32
// (reference uses jnp.float32 throughout; R0's bf16 guess produced NaN via
// fp32-bits-reinterpreted-as-bf16 NaN encodings).
//
// Per (k): 31 soft-LUT nodes. softmax(w) @ GATES collapses each node to 4
// floats (l0,l1,l2,l3); eval is a nested lerp. LUTs + leaf base offsets are
// recomputed per block into LDS (31 softmaxes — trivial vs. 27000 positions).

#define B_  4
#define C_  3
#define H_  32
#define W_  32
#define D_  32
#define K_  32
#define S_  16
#define OD_ 30
#define P_  27000   // 30*30*30
#define PPT 2       // positions per thread
#define TPB 256

__device__ __forceinline__ float lut_eval(const float* l, float a, float b) {
    // E[lut(a,b)] = l0*(1-a)(1-b) + l1*(1-a)b + l2*a(1-b) + l3*ab
    float t0 = fmaf(a, l[2] - l[0], l[0]);   // b=0 edge
    float t1 = fmaf(a, l[3] - l[1], l[1]);   // b=1 edge
    return fmaf(b, t1 - t0, t0);
}

__global__ __launch_bounds__(TPB) void logic_conv3d(
    const float* __restrict__ x,
    const int*   __restrict__ kc,
    const float* __restrict__ w0,
    const float* __restrict__ w1,
    const float* __restrict__ w2,
    const float* __restrict__ w3,
    const float* __restrict__ w4,
    float*       __restrict__ out)
{
    __shared__ float s_lut[31][4];   // node-major; reads are wave-uniform (broadcast)
    __shared__ int   s_base[32];     // [tree*16 + s] leaf offset in flattened (C,H,W,D)

    const int bk  = blockIdx.y;      // b*K + k
    const int b   = bk >> 5;         // K=32
    const int k   = bk & 31;
    const int tid = threadIdx.x;

    // ---- per-block setup: 31 softmax->LUT reductions + 32 base offsets ----
    if (tid < 31) {
        const float* wp; int ln;
        if      (tid < 16) { wp = w0; ln = tid;      }
        else if (tid < 24) { wp = w1; ln = tid - 16; }
        else if (tid < 28) { wp = w2; ln = tid - 24; }
        else if (tid < 30) { wp = w3; ln = tid - 28; }
        else               { wp = w4; ln = 0;        }
        const float* wrow = wp + (ln * K_ + k) * 16;
        float lg[16];
        float m = -1e30f;
        #pragma unroll
        for (int g = 0; g < 16; ++g) { lg[g] = wrow[g]; m = fmaxf(m, lg[g]); }
        float z = 0.f;
        #pragma unroll
        for (int g = 0; g < 16; ++g) { lg[g] = __expf(lg[g] - m); z += lg[g]; }
        const float inv = 1.0f / z;
        float l0 = 0.f, l1 = 0.f, l2 = 0.f, l3 = 0.f;
        #pragma unroll
        for (int g = 0; g < 16; ++g) {
            float p = lg[g] * inv;           // GATES[g,t] = (g>>t)&1, t = 2*a+b
            if (g & 1) l0 += p;
            if (g & 2) l1 += p;
            if (g & 4) l2 += p;
            if (g & 8) l3 += p;
        }
        s_lut[tid][0] = l0; s_lut[tid][1] = l1; s_lut[tid][2] = l2; s_lut[tid][3] = l3;
    } else if (tid >= 32 && tid < 64) {
        const int idx  = tid - 32;           // tree*16 + s
        const int tree = idx >> 4;
        const int s    = idx & 15;
        const int off  = ((tree * K_ + k) * S_ + s) * 4;  // kc layout (2,K,S,4) = (h,w,d,c)
        const int h = kc[off + 0], w = kc[off + 1], d = kc[off + 2], c = kc[off + 3];
        s_base[idx] = ((c * H_ + h) * W_ + w) * D_ + d;
    }
    __syncthreads();

    const float* xb = x + (size_t)b * (C_ * H_ * W_ * D_);
    const int p0 = blockIdx.x * (TPB * PPT) + tid;

    for (int it = 0; it < PPT; ++it) {
        const int p = p0 + it * TPB;
        if (p >= P_) break;
        const int oh = p / 900;
        const int r  = p - oh * 900;
        const int ow = r / 30;
        const int od = r - ow * 30;
        const int patch = (oh * W_ + ow) * D_ + od;

        float v[16];
        #pragma unroll
        for (int s = 0; s < 16; ++s) {
            const float a  = xb[s_base[s]      + patch];
            const float bb = xb[s_base[16 + s] + patch];
            v[s] = lut_eval(s_lut[s], a, bb);
        }
        // tree reduction: widths 8,4,2,1 at node offsets 16,24,28,30
        #pragma unroll
        for (int j = 0; j < 8; ++j) v[j] = lut_eval(s_lut[16 + j], v[2 * j], v[2 * j + 1]);
        #pragma unroll
        for (int j = 0; j < 4; ++j) v[j] = lut_eval(s_lut[24 + j], v[2 * j], v[2 * j + 1]);
        #pragma unroll
        for (int j = 0; j < 2; ++j) v[j] = lut_eval(s_lut[28 + j], v[2 * j], v[2 * j + 1]);
        v[0] = lut_eval(s_lut[30], v[0], v[1]);

        out[(size_t)bk * P_ + p] = v[0];
    }
}

extern "C" void kernel_launch(void* const* d_in, const int* in_sizes, int n_in,
                              void* d_out, int out_size, void* d_ws, size_t ws_size,
                              hipStream_t stream) {
    const float* x  = (const float*)d_in[0];
    const int*   kc = (const int*)d_in[1];
    const float* w0 = (const float*)d_in[2];
    const float* w1 = (const float*)d_in[3];
    const float* w2 = (const float*)d_in[4];
    const float* w3 = (const float*)d_in[5];
    const float* w4 = (const float*)d_in[6];
    float* out = (float*)d_out;

    dim3 grid((P_ + TPB * PPT - 1) / (TPB * PPT), B_ * K_);  // (53, 128)
    logic_conv3d<<<grid, TPB, 0, stream>>>(x, kc, w0, w1, w2, w3, w4, out);
}

// Round 3
// 106.217 us; speedup vs baseline: 1.0360x; 1.0360x over previous
//
#include <hip/hip_runtime.h>
#include <hip/hip_bf16.h>

// LogicConv3d: B=4, C=3, H=W=D=32, K=32, S=16 leaves, tree depth 4 (31 LUT nodes).
// Out: (B, K, 30, 30, 30) = 3,456,000 fp32 elements. All float tensors fp32.
//
// R2: register-cache all 31 node LUTs (delta form: E = l0 + a*d2 + b*d1 + ab*d3,
// 4 VALU/node), PPT=8 to amortize the LUT fill, scalar (SGPR) leaf base offsets.

#define B_  4
#define C_  3
#define H_  32
#define W_  32
#define D_  32
#define K_  32
#define S_  16
#define P_  27000   // 30*30*30
#define PPT 8       // positions per thread
#define TPB 256

__global__ __launch_bounds__(TPB, 2) void logic_conv3d(
    const float* __restrict__ x,
    const int*   __restrict__ kc,
    const float* __restrict__ w0,
    const float* __restrict__ w1,
    const float* __restrict__ w2,
    const float* __restrict__ w3,
    const float* __restrict__ w4,
    float*       __restrict__ out)
{
    __shared__ float s_lut[31][4];   // (l0, d1=l1-l0, d2=l2-l0, d3=l0-l1-l2+l3)
    __shared__ int   s_base[32];     // [tree*16 + s] leaf offset in flattened (C,H,W,D)

    const int bk  = blockIdx.y;      // b*K + k
    const int b   = bk >> 5;         // K=32
    const int k   = bk & 31;
    const int tid = threadIdx.x;

    // ---- per-block setup: 31 softmax->LUT reductions + 32 base offsets ----
    if (tid < 31) {
        const float* wp; int ln;
        if      (tid < 16) { wp = w0; ln = tid;      }
        else if (tid < 24) { wp = w1; ln = tid - 16; }
        else if (tid < 28) { wp = w2; ln = tid - 24; }
        else if (tid < 30) { wp = w3; ln = tid - 28; }
        else               { wp = w4; ln = 0;        }
        const float* wrow = wp + (ln * K_ + k) * 16;
        float lg[16];
        float m = -1e30f;
        #pragma unroll
        for (int g = 0; g < 16; ++g) { lg[g] = wrow[g]; m = fmaxf(m, lg[g]); }
        float z = 0.f;
        #pragma unroll
        for (int g = 0; g < 16; ++g) { lg[g] = __expf(lg[g] - m); z += lg[g]; }
        const float inv = 1.0f / z;
        float l0 = 0.f, l1 = 0.f, l2 = 0.f, l3 = 0.f;
        #pragma unroll
        for (int g = 0; g < 16; ++g) {
            float p = lg[g] * inv;           // GATES[g,t] = (g>>t)&1, t = 2*a+b
            if (g & 1) l0 += p;
            if (g & 2) l1 += p;
            if (g & 4) l2 += p;
            if (g & 8) l3 += p;
        }
        s_lut[tid][0] = l0;
        s_lut[tid][1] = l1 - l0;                 // d1 (coeff of b)
        s_lut[tid][2] = l2 - l0;                 // d2 (coeff of a)
        s_lut[tid][3] = (l3 - l2) - (l1 - l0);   // d3 (coeff of ab)
    } else if (tid >= 32 && tid < 64) {
        const int idx  = tid - 32;           // tree*16 + s
        const int tree = idx >> 4;
        const int s    = idx & 15;
        const int off  = ((tree * K_ + k) * S_ + s) * 4;  // kc layout (2,K,S,4) = (h,w,d,c)
        const int h = kc[off + 0], w = kc[off + 1], d = kc[off + 2], c = kc[off + 3];
        s_base[idx] = ((c * H_ + h) * W_ + w) * D_ + d;
    }
    __syncthreads();

    // ---- cache block-uniform LUTs into VGPRs, bases into SGPRs ----
    float Lc[31][4];
    #pragma unroll
    for (int n = 0; n < 31; ++n) {
        Lc[n][0] = s_lut[n][0]; Lc[n][1] = s_lut[n][1];
        Lc[n][2] = s_lut[n][2]; Lc[n][3] = s_lut[n][3];
    }
    int sb[32];
    #pragma unroll
    for (int s = 0; s < 32; ++s) sb[s] = __builtin_amdgcn_readfirstlane(s_base[s]);

    const float* xb = x + (size_t)b * (C_ * H_ * W_ * D_);
    float* outb = out + (size_t)bk * P_;
    const int p0 = blockIdx.x * (TPB * PPT) + tid;

    #pragma unroll
    for (int it = 0; it < PPT; ++it) {
        const int p = p0 + it * TPB;
        if (p < P_) {
            const int oh = p / 900;
            const int r  = p - oh * 900;
            const int ow = r / 30;
            const int od = r - ow * 30;
            const int patch = (oh * W_ + ow) * D_ + od;

            float v[16];
            #pragma unroll
            for (int s = 0; s < 16; ++s) {
                const float a  = xb[sb[s]      + patch];
                const float bb = xb[sb[16 + s] + patch];
                const float ab = a * bb;
                float t = fmaf(a, Lc[s][2], Lc[s][0]);
                t = fmaf(bb, Lc[s][1], t);
                v[s] = fmaf(ab, Lc[s][3], t);
            }
            #pragma unroll
            for (int lvl = 0; lvl < 4; ++lvl) {
                const int width = 8 >> lvl;              // 8,4,2,1
                const int nbase = (lvl == 0) ? 16 : (lvl == 1) ? 24 : (lvl == 2) ? 28 : 30;
                #pragma unroll
                for (int j = 0; j < width; ++j) {
                    const float a  = v[2 * j];
                    const float bb = v[2 * j + 1];
                    const float ab = a * bb;
                    float t = fmaf(a, Lc[nbase + j][2], Lc[nbase + j][0]);
                    t = fmaf(bb, Lc[nbase + j][1], t);
                    v[j] = fmaf(ab, Lc[nbase + j][3], t);
                }
            }
            outb[p] = v[0];
        }
    }
}

extern "C" void kernel_launch(void* const* d_in, const int* in_sizes, int n_in,
                              void* d_out, int out_size, void* d_ws, size_t ws_size,
                              hipStream_t stream) {
    const float* x  = (const float*)d_in[0];
    const int*   kc = (const int*)d_in[1];
    const float* w0 = (const float*)d_in[2];
    const float* w1 = (const float*)d_in[3];
    const float* w2 = (const float*)d_in[4];
    const float* w3 = (const float*)d_in[5];
    const float* w4 = (const float*)d_in[6];
    float* out = (float*)d_out;

    dim3 grid((P_ + TPB * PPT - 1) / (TPB * PPT), B_ * K_);  // (14, 128)
    logic_conv3d<<<grid, TPB, 0, stream>>>(x, kc, w0, w1, w2, w3, w4, out);
}